// Round 2
// baseline (617.602 us; speedup 1.0000x reference)
//
#include <hip/hip_runtime.h>

// RGCN layer, basis-decomposed.
// Inputs (setup_inputs order):
//   0: x        [50000,128]  f32
//   1: W_bases  [4,128,128]  f32   (used directly as GEMM B, flat [512,128])
//   2: w_comp   [16,4]       f32
//   3: norm     [1600000,1]  f32
//   4: src      [1600000]    i32
//   5: dst      [1600000]    i32
//   6: etype    [1600000]    i32
// Output: [50000,128] f32
//
// Identity (derived from the reference's permute/reshape scramble):
//   W_final[r, i2, o] = sum_b w_comp[i2%16, b] * W_bases[b, r*8 + i2/16, o]
//   => with i2 = 16j + t:
//   out[n,o] = sum_{b,k} W_bases[b,k,o] * aggB[n, b*128 + k],  k = et*8 + j
//   aggB[n, b*128 + et*8 + j] = sum_{e: dst=n} norm_e * xc[src_e, b*8 + j]
//   xc[n, b*8 + j] = sum_{t<16} x[n, 16j+t] * w_comp[t,b]        (edge-invariant!)
//
// Workspace layout (needs 108.8 MB):
//   aggB [50000][512] f32  at d_ws + 0          (102,400,000 B)
//   xc   [50000][32]  f32  at d_ws + 102400000  (  6,400,000 B)

#define N_NODES  50000
#define N_EDGES  1600000
#define IN_FEAT  128
#define OUT_FEAT 128
#define NUM_RELS 16
#define NUM_BASES 4
#define AGG_K    512   // NUM_BASES * 128
#define XC_K     32    // NUM_BASES * 8

// ---------------- Kernel 0: xc[n, b*8+j] = sum_t x[n,16j+t] * w_comp[t,b] ----
// 32 lanes per node (lane = b*8 + j), 8 nodes per 256-thread block pass.
__global__ __launch_bounds__(256) void node_precomp(
    const float* __restrict__ x, const float* __restrict__ w_comp,
    float* __restrict__ xc)
{
  const int lane = threadIdx.x & 31;
  const int grp  = threadIdx.x >> 5;
  const int j = lane & 7;
  const int b = lane >> 3;

  float wc[16];
  #pragma unroll
  for (int t = 0; t < 16; ++t) wc[t] = w_comp[t * NUM_BASES + b];

  for (int n = blockIdx.x * 8 + grp; n < N_NODES; n += gridDim.x * 8) {
    const float4* xr = (const float4*)(x + (size_t)n * IN_FEAT) + j * 4;
    float acc = 0.f;
    #pragma unroll
    for (int q = 0; q < 4; ++q) {
      float4 v = xr[q];
      acc += v.x * wc[q*4+0] + v.y * wc[q*4+1]
           + v.z * wc[q*4+2] + v.w * wc[q*4+3];
    }
    xc[(size_t)n * XC_K + lane] = acc;
  }
}

// ---------------- Kernel 1: edge scatter ----------------
// 32 lanes per edge (lane = b*8 + j):
//   atomicAdd(aggB[dst*512 + b*128 + et*8 + j], norm_e * xc[src*32 + lane])
__global__ __launch_bounds__(256) void edge_scatter(
    const float* __restrict__ xc, const float* __restrict__ norm,
    const int* __restrict__ src, const int* __restrict__ dst,
    const int* __restrict__ etype, float* __restrict__ agg)
{
  const int lane = threadIdx.x & 31;
  const int grp  = threadIdx.x >> 5;       // 8 edges per 256-thread block pass
  const int boff = (lane >> 3) * 128 + (lane & 7);

  for (int e = blockIdx.x * 8 + grp; e < N_EDGES; e += gridDim.x * 8) {
    const int   s  = src[e];
    const int   d  = dst[e];
    const int   et = etype[e];
    const float nm = norm[e];
    const float v  = xc[(size_t)s * XC_K + lane] * nm;   // 128B/edge, L2-hot
    // 32 lanes -> 4 groups of 8 consecutive floats: coalesced atomics.
    atomicAdd(agg + (size_t)d * AGG_K + boff + et * 8, v);
  }
}

// ---------------- Kernel 2: out = aggB[50000,512] @ Wb[512,128] ----------------
// fp32 vector GEMM (no fp32 MFMA on CDNA4). Tile M=128, N=64, KC=32.
// 128 threads; per-thread 8x8 micro-tile split (4+4)x(4+4) so all inner
// ds_read_b128 are bank-conflict-free. LDS bytes/FLOP = 64B / 128 FLOP.
#define TM 128
#define TN 64
#define KC 32

__device__ inline void fma4(float4& a, float s, const float4& b) {
  a.x += s * b.x; a.y += s * b.y; a.z += s * b.z; a.w += s * b.w;
}

__global__ __launch_bounds__(128) void gemm_out(
    const float* __restrict__ A,   // aggB [N_NODES][512]
    const float* __restrict__ B,   // W_bases flat [512][128]
    float* __restrict__ C)         // out [N_NODES][128]
{
  __shared__ float As[KC][TM + 4];      // k-major (transposed A tile)
  __shared__ float Bs[KC][TN];

  const int tid = threadIdx.x;          // 0..127
  const int tx  = tid & 7;              // cols: tx*4..+3 and 32+tx*4..+3
  const int ty  = tid >> 3;             // rows: ty*4..+3 and 64+ty*4..+3
  const int m0  = blockIdx.x * TM;
  const int n0  = blockIdx.y * TN;

  float4 acc[2][2][4];                  // [row-half][col-half][u]
  #pragma unroll
  for (int rh = 0; rh < 2; ++rh)
    #pragma unroll
    for (int ch = 0; ch < 2; ++ch)
      #pragma unroll
      for (int u = 0; u < 4; ++u)
        acc[rh][ch][u] = make_float4(0.f, 0.f, 0.f, 0.f);

  for (int kc = 0; kc < AGG_K; kc += KC) {
    // Stage A [128 rows x 32 k], transposed: 1024 float4 tasks / 8 per thread
    #pragma unroll
    for (int i = 0; i < 8; ++i) {
      int task = tid + 128 * i;
      int row  = task >> 3;            // 0..127
      int kq   = task & 7;             // float4 along k
      int gr   = m0 + row;
      float4 v = make_float4(0.f, 0.f, 0.f, 0.f);
      if (gr < N_NODES)
        v = *(const float4*)(A + (size_t)gr * AGG_K + kc + kq * 4);
      As[kq*4+0][row] = v.x; As[kq*4+1][row] = v.y;
      As[kq*4+2][row] = v.z; As[kq*4+3][row] = v.w;
    }
    // Stage B [32 k x 64 n]: 512 float4 tasks / 4 per thread
    #pragma unroll
    for (int i = 0; i < 4; ++i) {
      int task = tid + 128 * i;
      int k    = task >> 4;            // 0..31
      int nq   = task & 15;            // 0..15
      *(float4*)&Bs[k][nq * 4] =
          *(const float4*)(B + (size_t)(kc + k) * OUT_FEAT + n0 + nq * 4);
    }
    __syncthreads();

    #pragma unroll
    for (int k = 0; k < KC; ++k) {
      float4 a0 = *(const float4*)&As[k][ty * 4];
      float4 a1 = *(const float4*)&As[k][64 + ty * 4];
      float4 b0 = *(const float4*)&Bs[k][tx * 4];
      float4 b1 = *(const float4*)&Bs[k][32 + tx * 4];
      float ar0[4] = {a0.x, a0.y, a0.z, a0.w};
      float ar1[4] = {a1.x, a1.y, a1.z, a1.w};
      #pragma unroll
      for (int u = 0; u < 4; ++u) {
        fma4(acc[0][0][u], ar0[u], b0);
        fma4(acc[0][1][u], ar0[u], b1);
        fma4(acc[1][0][u], ar1[u], b0);
        fma4(acc[1][1][u], ar1[u], b1);
      }
    }
    __syncthreads();
  }

  #pragma unroll
  for (int rh = 0; rh < 2; ++rh) {
    #pragma unroll
    for (int u = 0; u < 4; ++u) {
      int r = m0 + rh * 64 + ty * 4 + u;
      if (r < N_NODES) {
        *(float4*)(C + (size_t)r * OUT_FEAT + n0 + tx * 4)      = acc[rh][0][u];
        *(float4*)(C + (size_t)r * OUT_FEAT + n0 + 32 + tx * 4) = acc[rh][1][u];
      }
    }
  }
}

// ---------------- Fallback (tiny d_ws): direct edge -> out atomics -------------
// One wave per edge. Lanes 0..31 (logically) compute m[b*8+j]; shuffle-broadcast;
// every lane accumulates 2 output columns and atomically adds into out[dst].
__global__ __launch_bounds__(256) void edge_direct(
    const float* __restrict__ x, const float* __restrict__ W_bases,
    const float* __restrict__ w_comp, const float* __restrict__ norm,
    const int* __restrict__ src, const int* __restrict__ dst,
    const int* __restrict__ etype, float* __restrict__ out)
{
  const int wave = threadIdx.x >> 6;
  const int lane = threadIdx.x & 63;
  const int j = lane & 7;
  const int b = (lane >> 3) & 3;

  float wc[16];
  #pragma unroll
  for (int t = 0; t < 16; ++t) wc[t] = w_comp[t * NUM_BASES + b];

  for (int e = blockIdx.x * 4 + wave; e < N_EDGES; e += gridDim.x * 4) {
    const int   s  = src[e];
    const int   d  = dst[e];
    const int   et = etype[e];
    const float nm = norm[e];

    // all 64 lanes compute (lanes 32..63 duplicate 0..31; only 0..31 consumed)
    const float4* xr = (const float4*)(x + (size_t)s * IN_FEAT) + j * 4;
    float m = 0.f;
    #pragma unroll
    for (int q = 0; q < 4; ++q) {
      float4 v = xr[q];
      m += v.x * wc[q*4+0] + v.y * wc[q*4+1]
         + v.z * wc[q*4+2] + v.w * wc[q*4+3];
    }
    m *= nm;

    float acc0 = 0.f, acc1 = 0.f;
    #pragma unroll
    for (int p = 0; p < 32; ++p) {
      float mv = __shfl(m, p, 64);
      const float* Wr = W_bases + (size_t)((p >> 3) * 128 + et * 8 + (p & 7)) * OUT_FEAT;
      acc0 += mv * Wr[lane];
      acc1 += mv * Wr[64 + lane];
    }
    atomicAdd(out + (size_t)d * OUT_FEAT + lane, acc0);
    atomicAdd(out + (size_t)d * OUT_FEAT + 64 + lane, acc1);
  }
}

extern "C" void kernel_launch(void* const* d_in, const int* in_sizes, int n_in,
                              void* d_out, int out_size, void* d_ws, size_t ws_size,
                              hipStream_t stream) {
  const float* x       = (const float*)d_in[0];
  const float* W_bases = (const float*)d_in[1];
  const float* w_comp  = (const float*)d_in[2];
  const float* norm    = (const float*)d_in[3];
  const int*   src     = (const int*)d_in[4];
  const int*   dst     = (const int*)d_in[5];
  const int*   etype   = (const int*)d_in[6];
  float* out = (float*)d_out;

  const size_t agg_bytes = (size_t)N_NODES * AGG_K * sizeof(float);  // 102.4 MB
  const size_t xc_bytes  = (size_t)N_NODES * XC_K  * sizeof(float);  //   6.4 MB

  if (ws_size >= agg_bytes + xc_bytes) {
    float* aggB = (float*)d_ws;
    float* xc   = (float*)((char*)d_ws + agg_bytes);

    hipMemsetAsync(aggB, 0, agg_bytes, stream);
    node_precomp<<<6250, 256, 0, stream>>>(x, w_comp, xc);
    edge_scatter<<<8192, 256, 0, stream>>>(xc, norm, src, dst, etype, aggB);

    dim3 ggrid((N_NODES + TM - 1) / TM, OUT_FEAT / TN);   // (391, 2)
    gemm_out<<<ggrid, 128, 0, stream>>>(aggB, W_bases, out);
  } else {
    // Correctness fallback for small workspace: direct scatter into out.
    hipMemsetAsync(out, 0, (size_t)out_size * sizeof(float), stream);
    edge_direct<<<8192, 256, 0, stream>>>(x, W_bases, w_comp, norm,
                                          src, dst, etype, out);
  }
}

// Round 3
// 461.203 us; speedup vs baseline: 1.3391x; 1.3391x over previous
//
#include <hip/hip_runtime.h>

// RGCN layer, basis-decomposed, atomic-free aggregation via dst-binning.
//
// Identity (validated in round 2, absmax 0.125 pass):
//   xc[n, b*8+j]  = sum_{t<16} x[n, 16j+t] * w_comp[t,b]
//   acc[n, b*128 + et*8 + j] = sum_{e: dst=n} norm_e * xc[src_e, b*8+j]
//   out[n,o] = sum_{k2} acc[n,k2] * WbFlat[k2,o],  WbFlat = W_bases as [512,128]
//
// Pipeline:
//   memset(cnt,spillcnt) -> node_precomp(x->xc) -> bin_edges(dst bins)
//   -> rgcn_fused (per-node LDS accumulate + 8-node block GEMM -> out)
//   -> spill_fix (bin-overflow edges, normally zero)
//
// Workspace layout (51.4 MB, well under the 108.8 MB proven available):
//   [0,200000)            cnt[50000] i32
//   [200000,200064)       spillcnt i32 (+pad)
//   [200064,6600064)      spill[1.6M] i32
//   [6600064,45000064)    bins[50000][96] uint2 {src|(et<<17), norm bits}
//   [45000064,51400064)   xc[50000][32] f32

#define N_NODES  50000
#define N_EDGES  1600000
#define IN_FEAT  128
#define OUT_FEAT 128
#define NUM_RELS 16
#define NUM_BASES 4
#define XC_K     32
#define BIN_CAP  96

#define OFF_CNT      0
#define OFF_SPILLCNT 200000
#define OFF_SPILL    200064
#define OFF_BINS     6600064
#define OFF_XC       45000064
#define WS_NEED      51400064

// ---------------- xc[n, b*8+j] = sum_t x[n,16j+t] * w_comp[t,b] ----------------
__global__ __launch_bounds__(256) void node_precomp(
    const float* __restrict__ x, const float* __restrict__ w_comp,
    float* __restrict__ xc)
{
  const int lane = threadIdx.x & 31;
  const int grp  = threadIdx.x >> 5;
  const int j = lane & 7;
  const int b = lane >> 3;

  float wc[16];
  #pragma unroll
  for (int t = 0; t < 16; ++t) wc[t] = w_comp[t * NUM_BASES + b];

  for (int n = blockIdx.x * 8 + grp; n < N_NODES; n += gridDim.x * 8) {
    const float4* xr = (const float4*)(x + (size_t)n * IN_FEAT) + j * 4;
    float acc = 0.f;
    #pragma unroll
    for (int q = 0; q < 4; ++q) {
      float4 v = xr[q];
      acc += v.x * wc[q*4+0] + v.y * wc[q*4+1]
           + v.z * wc[q*4+2] + v.w * wc[q*4+3];
    }
    xc[(size_t)n * XC_K + lane] = acc;
  }
}

// ---------------- bin edges by dst ----------------
__global__ __launch_bounds__(256) void bin_edges(
    const int* __restrict__ src, const int* __restrict__ dst,
    const int* __restrict__ etype, const float* __restrict__ norm,
    int* __restrict__ cnt, uint2* __restrict__ bins,
    int* __restrict__ spillcnt, int* __restrict__ spill)
{
  for (int e = blockIdx.x * blockDim.x + threadIdx.x; e < N_EDGES;
       e += gridDim.x * blockDim.x) {
    const int d  = dst[e];
    const int s  = src[e];
    const int et = etype[e];
    const float nm = norm[e];
    const int pos = atomicAdd(&cnt[d], 1);
    if (pos < BIN_CAP) {
      bins[(size_t)d * BIN_CAP + pos] =
          make_uint2((unsigned)s | ((unsigned)et << 17), __float_as_uint(nm));
    } else {
      const int k = atomicAdd(spillcnt, 1);
      if (k < N_EDGES) spill[k] = e;
    }
  }
}

// ---------------- fused gather + GEMM ----------------
// 512 threads = 8 waves; each wave owns one node in phase A.
// LDS acc: 8 waves x 2 halves x 512 floats (perm layout slot = (et*8+j)*4 + b
// -> 32 lanes of a half-wave hit 32 distinct banks; two halves alias 2-way = free).
// Phase B: block-wide GEMM out[8][128] = acc[8][512] @ WbFlat[512][128],
// Wb reads coalesced across o and amortized over 8 nodes.
__global__ __launch_bounds__(512) void rgcn_fused(
    const int* __restrict__ cnt, const uint2* __restrict__ bins,
    const float* __restrict__ xc, const float* __restrict__ Wb,
    float* __restrict__ out)
{
  __shared__ float acc[8 * 1024];   // 32 KB

  const int t    = threadIdx.x;
  const int w    = t >> 6;          // wave id 0..7
  const int lane = t & 63;
  const int h    = lane >> 5;       // half 0/1
  const int l5   = lane & 31;       // slot lane: b = l5>>3, j = l5&7
  const int jj4b = (l5 & 7) * 4 + (l5 >> 3);   // perm slot low bits
  const int accBase = w * 1024 + h * 512;

  const int nodeBase = blockIdx.x * 8;
  const int n = nodeBase + w;       // this wave's node (grid sized exactly)

  // zero this wave's acc region (1024 floats, 16 per lane)
  #pragma unroll
  for (int q = 0; q < 4; ++q)
    *(float4*)&acc[w * 1024 + lane * 16 + q * 4] = make_float4(0.f,0.f,0.f,0.f);

  int cntv = 0;
  uint32_t B0x = 0, B0y = 0, B1x = 0, B1y = 0;
  if (n < N_NODES) {
    cntv = cnt[n]; if (cntv > BIN_CAP) cntv = BIN_CAP;
    const uint2* bp = bins + (size_t)n * BIN_CAP;
    uint2 v0 = bp[lane];  B0x = v0.x; B0y = v0.y;       // edges 0..63
    uint2 v1 = bp[(lane & 31) + 64]; B1x = v1.x; B1y = v1.y; // edges 64..95
  }

  // phase A: half h processes edges 2i+h, accumulating into its LDS copy.
  const int iters = (cntv + 1) >> 1;
  // software pipeline depth 1 on the xc gather
  int   idx  = h;
  bool  act0 = idx < cntv;
  uint32_t wx = (idx < 64) ? __shfl(B0x, idx) : __shfl(B1x, (idx - 64) & 31);
  uint32_t wy = (idx < 64) ? __shfl(B0y, idx) : __shfl(B1y, (idx - 64) & 31);
  int   s0  = wx & 0x1FFFF;
  int   et0 = (wx >> 17) & 15;
  float nm0 = __uint_as_float(wy);
  float xc0 = act0 ? xc[(size_t)s0 * XC_K + l5] : 0.f;

  for (int i = 0; i < iters; ++i) {
    // prefetch stage i+1
    const int idx1 = 2 * (i + 1) + h;
    const bool act1 = idx1 < cntv;
    uint32_t nx = (idx1 < 64) ? __shfl(B0x, idx1) : __shfl(B1x, (idx1 - 64) & 31);
    uint32_t ny = (idx1 < 64) ? __shfl(B0y, idx1) : __shfl(B1y, (idx1 - 64) & 31);
    const int   s1  = nx & 0x1FFFF;
    const int   et1 = (nx >> 17) & 15;
    const float nm1 = __uint_as_float(ny);
    const float xc1 = act1 ? xc[(size_t)s1 * XC_K + l5] : 0.f;
    // consume stage i
    if (act0) {
      const int slot = accBase + et0 * 32 + jj4b;
      acc[slot] += xc0 * nm0;
    }
    act0 = act1; xc0 = xc1; et0 = et1; nm0 = nm1;
  }

  // merge half 1 into half 0 (wave-private region, no barrier needed yet)
  #pragma unroll
  for (int q = 0; q < 8; ++q) {
    const int idxm = w * 1024 + q * 64 + lane;
    acc[idxm] += acc[idxm + 512];
  }
  __syncthreads();

  // phase B: 512 threads -> o = t&127, g = t>>7 handles nodes 2g, 2g+1.
  const int o  = t & 127;
  const int g  = t >> 7;
  const float* a0p = &acc[(2 * g) * 1024];
  const float* a1p = &acc[(2 * g + 1) * 1024];
  const float* wp0 = Wb + o;                    // row k2 -> wp0[k2*128]
  float o0 = 0.f, o1 = 0.f;
  #pragma unroll 4
  for (int m = 0; m < 128; ++m) {
    const float4 a0 = *(const float4*)&a0p[m * 4];   // b=0..3 of k2=b*128+m
    const float4 a1 = *(const float4*)&a1p[m * 4];
    const float w0 = wp0[(m          ) * 128];
    const float w1 = wp0[(m + 128    ) * 128];
    const float w2 = wp0[(m + 256    ) * 128];
    const float w3 = wp0[(m + 384    ) * 128];
    o0 += a0.x * w0 + a0.y * w1 + a0.z * w2 + a0.w * w3;
    o1 += a1.x * w0 + a1.y * w1 + a1.z * w2 + a1.w * w3;
  }
  const int n0 = nodeBase + 2 * g;
  const int n1 = n0 + 1;
  if (n0 < N_NODES) out[(size_t)n0 * OUT_FEAT + o] = o0;
  if (n1 < N_NODES) out[(size_t)n1 * OUT_FEAT + o] = o1;
}

// ---------------- spill fix (bin overflow; normally 0 edges) ----------------
__global__ __launch_bounds__(256) void spill_fix(
    const int* __restrict__ spillcnt, const int* __restrict__ spill,
    const float* __restrict__ xc, const float* __restrict__ Wb,
    const float* __restrict__ norm, const int* __restrict__ src,
    const int* __restrict__ dst, const int* __restrict__ etype,
    float* __restrict__ out)
{
  int cntv = *spillcnt; if (cntv > N_EDGES) cntv = N_EDGES;
  for (int idx = blockIdx.x * blockDim.x + threadIdx.x; idx < cntv;
       idx += gridDim.x * blockDim.x) {
    const int e = spill[idx];
    const int s = src[e], d = dst[e], et = etype[e];
    const float nm = norm[e];
    float m[32];
    #pragma unroll
    for (int l = 0; l < 32; ++l) m[l] = xc[(size_t)s * XC_K + l] * nm;
    for (int o = 0; o < OUT_FEAT; ++o) {
      float a = 0.f;
      #pragma unroll
      for (int l = 0; l < 32; ++l)
        a += m[l] * Wb[(size_t)((l >> 3) * 128 + et * 8 + (l & 7)) * OUT_FEAT + o];
      atomicAdd(&out[(size_t)d * OUT_FEAT + o], a);
    }
  }
}

// ---------------- fallback (tiny d_ws): direct edge -> out atomics ------------
__global__ __launch_bounds__(256) void edge_direct(
    const float* __restrict__ x, const float* __restrict__ W_bases,
    const float* __restrict__ w_comp, const float* __restrict__ norm,
    const int* __restrict__ src, const int* __restrict__ dst,
    const int* __restrict__ etype, float* __restrict__ out)
{
  const int wave = threadIdx.x >> 6;
  const int lane = threadIdx.x & 63;
  const int j = lane & 7;
  const int b = (lane >> 3) & 3;

  float wc[16];
  #pragma unroll
  for (int t = 0; t < 16; ++t) wc[t] = w_comp[t * NUM_BASES + b];

  for (int e = blockIdx.x * 4 + wave; e < N_EDGES; e += gridDim.x * 4) {
    const int   s  = src[e];
    const int   d  = dst[e];
    const int   et = etype[e];
    const float nm = norm[e];
    const float4* xr = (const float4*)(x + (size_t)s * IN_FEAT) + j * 4;
    float m = 0.f;
    #pragma unroll
    for (int q = 0; q < 4; ++q) {
      float4 v = xr[q];
      m += v.x * wc[q*4+0] + v.y * wc[q*4+1]
         + v.z * wc[q*4+2] + v.w * wc[q*4+3];
    }
    m *= nm;
    float acc0 = 0.f, acc1 = 0.f;
    #pragma unroll
    for (int p = 0; p < 32; ++p) {
      float mv = __shfl(m, p, 64);
      const float* Wr = W_bases + (size_t)((p >> 3) * 128 + et * 8 + (p & 7)) * OUT_FEAT;
      acc0 += mv * Wr[lane];
      acc1 += mv * Wr[64 + lane];
    }
    atomicAdd(out + (size_t)d * OUT_FEAT + lane, acc0);
    atomicAdd(out + (size_t)d * OUT_FEAT + 64 + lane, acc1);
  }
}

extern "C" void kernel_launch(void* const* d_in, const int* in_sizes, int n_in,
                              void* d_out, int out_size, void* d_ws, size_t ws_size,
                              hipStream_t stream) {
  const float* x       = (const float*)d_in[0];
  const float* W_bases = (const float*)d_in[1];   // flat [512][128] as WbFlat
  const float* w_comp  = (const float*)d_in[2];
  const float* norm    = (const float*)d_in[3];
  const int*   src     = (const int*)d_in[4];
  const int*   dst     = (const int*)d_in[5];
  const int*   etype   = (const int*)d_in[6];
  float* out = (float*)d_out;

  if (ws_size >= (size_t)WS_NEED) {
    char* ws = (char*)d_ws;
    int*   cntp     = (int*)(ws + OFF_CNT);
    int*   spillcnt = (int*)(ws + OFF_SPILLCNT);
    int*   spill    = (int*)(ws + OFF_SPILL);
    uint2* bins     = (uint2*)(ws + OFF_BINS);
    float* xc       = (float*)(ws + OFF_XC);

    hipMemsetAsync(cntp, 0, 200064, stream);  // cnt + spillcnt
    node_precomp<<<6250, 256, 0, stream>>>(x, w_comp, xc);
    bin_edges<<<6250, 256, 0, stream>>>(src, dst, etype, norm,
                                        cntp, bins, spillcnt, spill);
    rgcn_fused<<<(N_NODES + 7) / 8, 512, 0, stream>>>(cntp, bins, xc, W_bases, out);
    spill_fix<<<16, 256, 0, stream>>>(spillcnt, spill, xc, W_bases,
                                      norm, src, dst, etype, out);
  } else {
    hipMemsetAsync(out, 0, (size_t)out_size * sizeof(float), stream);
    edge_direct<<<8192, 256, 0, stream>>>(x, W_bases, w_comp, norm,
                                          src, dst, etype, out);
  }
}